// Round 1
// 424.084 us; speedup vs baseline: 1.0070x; 1.0070x over previous
//
#include <hip/hip_runtime.h>
#include <cstdint>
#include <cstddef>

#define NN    8192      // N
#define NIN   4096      // N_IN
#define BB    16        // B
#define BN    131072    // B*N
#define ROWCH 256       // rows per chunk (512->256: grid 16x48 = 768 = 3 blocks/CU exactly)
#define NCHI  32        // int chunks  (8192/256)
#define NCHE  16        // ext chunks  (4096/256)
#define NCH   48        // total chunks

static constexpr float ALPHA_F = 0.9512294245007140f;               // fl32(exp(-0.05))
static constexpr float RHOA_F  = 0.9950124791926823f;               // fl32(exp(-0.005))
static constexpr float SCALE_F = (float)(1.0 - 0.9512294245007140); // fl32(1 - alpha)

// ---------------------------------------------------------------------------
// k_aux: (a) per-row spike bit-masks from Xd[-1] / Xext, (b) delay-buffer
// shift Xd_new[1:8] = Xd[0:7] (float4). Grid-stride over 7*BN/4 float4s.
// ---------------------------------------------------------------------------
__global__ __launch_bounds__(256) void k_aux(
    const float* __restrict__ Xd, const float* __restrict__ Xext,
    float* __restrict__ out,
    unsigned* __restrict__ mask_int, unsigned* __restrict__ mask_ext)
{
    const int t = blockIdx.x * 256 + threadIdx.x;   // [0, 7*BN/4)

    if (t < NN) {                       // internal mask from Xd[-1]
        unsigned m = 0;
        #pragma unroll
        for (int b = 0; b < BB; ++b)
            m |= (Xd[7*BN + b*NN + t] > 0.5f) ? (1u << b) : 0u;
        mask_int[t] = m;
    } else if (t < NN + NIN) {          // external mask from Xext
        const int i = t - NN;
        unsigned m = 0;
        #pragma unroll
        for (int b = 0; b < BB; ++b)
            m |= (Xext[b*NIN + i] > 0.5f) ? (1u << b) : 0u;
        mask_ext[i] = m;
    }

    // shift: Xd_new[1:8] = Xd[0:7]
    ((float4*)(out + (size_t)4*BN))[t] = ((const float4*)Xd)[t];
}

// ---------------------------------------------------------------------------
// k_mm: spike-sparse matmul with per-block row compaction.
// grid = (16 col-tiles of 512, NCH chunks). y<NCHI -> W_int rows, else W_ext.
// Each block: stage 256 masks -> compact active rows in LDS (1 ballot round)
// -> explicitly software-pipelined 8-deep load/FMA groups (prefetch group
// j+8's entries+rows during group j's FMAs, hiding ~900cy HBM latency).
// Partials to ws.
// ---------------------------------------------------------------------------
__device__ __forceinline__ void accrow(float2 (&acc)[BB], unsigned m, float wx, float wy)
{
    #pragma unroll
    for (int b = 0; b < BB; ++b) {
        const float f = (float)((m >> b) & 1u);
        acc[b].x = __builtin_fmaf(wx, f, acc[b].x);
        acc[b].y = __builtin_fmaf(wy, f, acc[b].y);
    }
}

__global__ __launch_bounds__(256) void k_mm(
    const float* __restrict__ Wint, const float* __restrict__ Wext,
    const unsigned* __restrict__ mask_int, const unsigned* __restrict__ mask_ext,
    float* __restrict__ part)
{
    const int tid  = threadIdx.x;
    const int y    = blockIdx.y;
    const int wave = tid >> 6, lane = tid & 63;
    const bool is_int = (y < NCHI);
    const float*    W    = is_int ? Wint : Wext;
    const unsigned* mask = is_int ? mask_int : mask_ext;
    const int base_row   = (is_int ? y : (y - NCHI)) * ROWCH;

    __shared__ unsigned sc[ROWCH + 16];  // compacted (localrow<<16)|mask, +16 zero pad
    __shared__ unsigned wsum[4];

    // --- per-block compaction of 256 masks (single ballot round) ---
    const unsigned m = mask[base_row + tid];
    const unsigned long long bal = __ballot(m != 0);
    const unsigned pre = __popcll(bal & ((1ull << lane) - 1ull));
    if (lane == 0) wsum[wave] = (unsigned)__popcll(bal);
    __syncthreads();
    const unsigned w0 = wsum[0], w1 = wsum[1], w2 = wsum[2], w3 = wsum[3];
    unsigned bw = 0;
    if (wave > 0) bw += w0;
    if (wave > 1) bw += w1;
    if (wave > 2) bw += w2;
    const unsigned total = w0 + w1 + w2 + w3;
    if (m) sc[bw + pre] = ((unsigned)tid << 16) | m;
    if (tid < 16) sc[total + tid] = 0u;   // zero-pad: covers trailing group + prefetch overrun
    __syncthreads();
    const unsigned nrow8 = (total + 7u) & ~7u;

    // --- double-buffered 8-deep pipeline over active rows ---
    const int n = (blockIdx.x << 9) + (tid << 1);   // 2 cols/thread, 512-col tile
    float2 acc[BB];
    #pragma unroll
    for (int b = 0; b < BB; ++b) acc[b] = make_float2(0.f, 0.f);

    const float* Wb = W + (size_t)base_row * NN + n;

    // prime group 0
    unsigned eA[8]; float2 wA[8];
    #pragma unroll
    for (int k = 0; k < 8; ++k) eA[k] = sc[k];
    #pragma unroll
    for (int k = 0; k < 8; ++k)
        wA[k] = *(const float2*)(Wb + (int)(eA[k] >> 16) * NN);

    for (unsigned j = 0; j < nrow8; j += 8) {
        // prefetch group j+8 (reads land in zero-pad past the end: row 0, mask 0)
        unsigned eB[8]; float2 wB[8];
        #pragma unroll
        for (int k = 0; k < 8; ++k) eB[k] = sc[j + 8 + k];
        #pragma unroll
        for (int k = 0; k < 8; ++k)
            wB[k] = *(const float2*)(Wb + (int)(eB[k] >> 16) * NN);
        // consume group j (its loads were issued one full FMA-phase ago)
        #pragma unroll
        for (int k = 0; k < 8; ++k)
            accrow(acc, eA[k] & 0xffffu, wA[k].x, wA[k].y);
        // rotate
        #pragma unroll
        for (int k = 0; k < 8; ++k) { eA[k] = eB[k]; wA[k] = wB[k]; }
    }

    float* p = part + (size_t)y * BN + n;
    #pragma unroll
    for (int b = 0; b < BB; ++b)
        *(float2*)(p + (size_t)b * NN) = acc[b];
}

// ---------------------------------------------------------------------------
// k_fin: fused ALIF elementwise + partial reduction (48 partials).
// out layout: [X (BN) | V_new (BN) | a_new (BN) | Xd_new (8*BN)]
// 128-thread blocks -> 256 blocks so the reduction uses the whole chip.
// ---------------------------------------------------------------------------
__global__ __launch_bounds__(128) void k_fin(
    const float* __restrict__ V, const float* __restrict__ a,
    const float* __restrict__ part, float* __restrict__ out)
{
    const int t4 = blockIdx.x * 128 + threadIdx.x;  // [0, BN/4)

    float4 s = make_float4(0.f, 0.f, 0.f, 0.f);
    #pragma unroll 8
    for (int c = 0; c < NCH; ++c) {
        const float4 p = ((const float4*)(part + (size_t)c * BN))[t4];
        s.x += p.x; s.y += p.y; s.z += p.z; s.w += p.w;
    }

    const float4 v4 = ((const float4*)V)[t4];
    const float4 a4 = ((const float4*)a)[t4];
    float4 x4, vn4, an4;
    {
        const float* vv = &v4.x; const float* aa = &a4.x;
        float* xx = &x4.x; float* vn = &vn4.x; float* an = &an4.x;
        const float* ss = &s.x;
        #pragma unroll
        for (int k = 0; k < 4; ++k) {
            // exactness-critical: no FMA contraction on the threshold compare
            const float th = __fadd_rn(1.0f, __fmul_rn(1.8f, aa[k]));
            const bool spike = (vv[k] >= th);
            const float x = spike ? 1.0f : 0.0f;
            xx[k] = x;
            float v_new = spike ? 0.0f : __fmul_rn(ALPHA_F, vv[k]);
            vn[k] = __builtin_fmaf(SCALE_F, ss[k], v_new);
            an[k] = __fadd_rn(__fmul_rn(RHOA_F, aa[k]), x);
        }
    }
    ((float4*)out)[t4]                       = x4;   // X
    ((float4*)(out + (size_t)BN))[t4]        = vn4;  // V_new
    ((float4*)(out + (size_t)2*BN))[t4]      = an4;  // a_new
    ((float4*)(out + (size_t)3*BN))[t4]      = x4;   // Xd_new[0]
}

// ---------------------------------------------------------------------------
extern "C" void kernel_launch(void* const* d_in, const int* in_sizes, int n_in,
                              void* d_out, int out_size, void* d_ws, size_t ws_size,
                              hipStream_t stream)
{
    const float* V    = (const float*)d_in[0];
    const float* a    = (const float*)d_in[1];
    const float* Xd   = (const float*)d_in[2];
    const float* Xext = (const float*)d_in[3];
    const float* Wint = (const float*)d_in[4];
    const float* Wext = (const float*)d_in[5];
    float* out = (float*)d_out;

    unsigned* mask_int = (unsigned*)d_ws;                    // 8192 u32
    unsigned* mask_ext = mask_int + NN;                      // 4096 u32
    float*    part     = (float*)((char*)d_ws + 65536);      // NCH*BN f32 (25.2 MB)

    k_aux<<<(7*BN/4)/256, 256, 0, stream>>>(Xd, Xext, out, mask_int, mask_ext);
    k_mm<<<dim3(16, NCH), 256, 0, stream>>>(Wint, Wext, mask_int, mask_ext, part);
    k_fin<<<BN/4/128, 128, 0, stream>>>(V, a, part, out);
}